// Round 17
// baseline (207.753 us; speedup 1.0000x reference)
//
#include <hip/hip_runtime.h>
#include <math.h>

#define F1 256
#define F2 128
#define F3 40
#define H2S 64    // h2 fp8 row stride in bytes (16 dwords; 10 valid + zero pad)
#define RPB 256
#define RSH 8
#define TPB 8192

typedef unsigned short ushort_t;
typedef unsigned char uchar_t;
typedef unsigned int uint_t;
typedef __attribute__((ext_vector_type(8))) short bf16x8;
typedef __attribute__((ext_vector_type(4))) float f32x4;
typedef __attribute__((ext_vector_type(2))) float f32x2;

__device__ inline ushort_t f2bf(float f) {
  unsigned u = __builtin_bit_cast(unsigned, f);
  u += 0x7FFF + ((u >> 16) & 1);
  return (ushort_t)(u >> 16);
}
__device__ inline float bf2f(ushort_t b) {
  unsigned u = ((unsigned)b) << 16;
  return __builtin_bit_cast(float, u);
}
__device__ inline float i2f(int b) { return __builtin_bit_cast(float, b); }
__device__ inline uchar_t f2fp8(float f) {
  return (uchar_t)(__builtin_amdgcn_cvt_pk_fp8_f32(f, 0.f, 0, false) & 0xff);
}
__device__ inline f32x2 fp8lo(unsigned u) { return __builtin_amdgcn_cvt_pk_f32_fp8(u, false); }
__device__ inline f32x2 fp8hi(unsigned u) { return __builtin_amdgcn_cvt_pk_f32_fp8(u, true); }
__device__ inline long long nt_ld_rec(const long long* p) {
  return __builtin_nontemporal_load(p);
}
__device__ inline int rec_col(long long r) { return (int)(unsigned)(r & 0xffffffffll); }
__device__ inline float rec_w(long long r) { return i2f((int)(unsigned)(((unsigned long long)r) >> 32)); }

// ---------------- CSR build: 2-level counting sort ----------------

__global__ __launch_bounds__(256) void k_cnt(const int* __restrict__ row, int* __restrict__ cnt,
                                             int E, int G, int NBIN) {
  __shared__ int h[400];
  int tid = threadIdx.x, blk = blockIdx.x;
  for (int i = tid; i < NBIN; i += 256) h[i] = 0;
  __syncthreads();
  int base = blk * TPB, lim = min(base + TPB, E);
  for (int i = base + tid; i < lim; i += 256) atomicAdd(&h[row[i] >> RSH], 1);
  __syncthreads();
  for (int i = tid; i < NBIN; i += 256) cnt[i * G + blk] = h[i];
}

__global__ __launch_bounds__(256) void k_scan1(const int* __restrict__ in, int* __restrict__ out,
                                               int* __restrict__ aux, int n) {
  __shared__ int lds[256];
  int tid = threadIdx.x;
  int base = blockIdx.x * 1024 + tid * 4;
  int v0 = 0, v1 = 0, v2 = 0, v3 = 0;
  if (base + 0 < n) v0 = in[base + 0];
  if (base + 1 < n) v1 = in[base + 1];
  if (base + 2 < n) v2 = in[base + 2];
  if (base + 3 < n) v3 = in[base + 3];
  int s = v0 + v1 + v2 + v3;
  lds[tid] = s;
  __syncthreads();
  for (int off = 1; off < 256; off <<= 1) {
    int t = (tid >= off) ? lds[tid - off] : 0;
    __syncthreads();
    lds[tid] += t;
    __syncthreads();
  }
  int excl = (tid > 0) ? lds[tid - 1] : 0;
  if (tid == 255) aux[blockIdx.x] = lds[255];
  if (base + 0 < n) out[base + 0] = excl;
  if (base + 1 < n) out[base + 1] = excl + v0;
  if (base + 2 < n) out[base + 2] = excl + v0 + v1;
  if (base + 3 < n) out[base + 3] = excl + v0 + v1 + v2;
}

__global__ __launch_bounds__(128) void k_scan_aux(int* __restrict__ aux, int nb) {
  __shared__ int lds[128];
  int tid = threadIdx.x;
  int v = (tid < nb) ? aux[tid] : 0;
  lds[tid] = v;
  __syncthreads();
  for (int off = 1; off < 128; off <<= 1) {
    int t = (tid >= off) ? lds[tid - off] : 0;
    __syncthreads();
    lds[tid] += t;
    __syncthreads();
  }
  int excl = (tid > 0) ? lds[tid - 1] : 0;
  if (tid < nb) aux[tid] = excl;
}

__global__ __launch_bounds__(256) void k_scan_add(int* __restrict__ out, const int* __restrict__ aux,
                                                  int n, int E) {
  int add = aux[blockIdx.x];
  int base = blockIdx.x * 1024 + threadIdx.x * 4;
#pragma unroll
  for (int i = 0; i < 4; i++)
    if (base + i < n) out[base + i] += add;
  if (blockIdx.x == 0 && threadIdx.x == 0) out[n] = E;
}

__global__ __launch_bounds__(256) void k_scatter1(const int* __restrict__ row, const int* __restrict__ col,
                                                  const float* __restrict__ w, const int* __restrict__ cntoff,
                                                  int2* __restrict__ epk2, int E, int G, int NBIN) {
  __shared__ int cur[400];
  int tid = threadIdx.x, blk = blockIdx.x;
  for (int i = tid; i < NBIN; i += 256) cur[i] = cntoff[i * G + blk];
  __syncthreads();
  int base = blk * TPB, lim = min(base + TPB, E);
  for (int i = base + tid; i < lim; i += 256) {
    int r = row[i];
    int pos = atomicAdd(&cur[r >> RSH], 1);
    epk2[pos] = make_int2(((r & (RPB - 1)) << 17) | col[i], __builtin_bit_cast(int, w[i]));
  }
}

__global__ __launch_bounds__(256) void k_binsort(const int* __restrict__ cntoff, const int2* __restrict__ epk2,
                                                 int* __restrict__ ip, int2* __restrict__ epk,
                                                 int G, int NBIN, int N, int E) {
  __shared__ int sc[256], cur[256];
  int tid = threadIdx.x, b = blockIdx.x;
  int s = cntoff[b * G], eend = cntoff[(b + 1) * G];
  cur[tid] = 0;
  __syncthreads();
  for (int i = s + tid; i < eend; i += 256) atomicAdd(&cur[epk2[i].x >> 17], 1);
  __syncthreads();
  int d = cur[tid];
  sc[tid] = d;
  __syncthreads();
  for (int o = 1; o < 256; o <<= 1) {
    int t = (tid >= o) ? sc[tid - o] : 0;
    __syncthreads();
    sc[tid] += t;
    __syncthreads();
  }
  int excl = (tid > 0) ? sc[tid - 1] : 0;
  __syncthreads();
  cur[tid] = excl;
  int gr = (b << RSH) + tid;
  if (gr <= N) ip[gr] = s + excl;
  if (b == 0 && tid == 0) ip[N] = E;
  __syncthreads();
  for (int i = s + tid; i < eend; i += 256) {
    int2 rec = epk2[i];
    int local = rec.x >> 17, c = rec.x & 0x1FFFF;
    int p = s + atomicAdd(&cur[local], 1);
    epk[p] = make_int2(c, rec.y);
  }
}

// ---------------- W1 prep ----------------
__global__ __launch_bounds__(256) void k_w1prep(const float* __restrict__ W1, ushort_t* __restrict__ w1pf) {
  int idx = blockIdx.x * 256 + threadIdx.x;
  if (idx < 8 * 8 * 64 * 8) {
    int j = idx & 7;
    int l = (idx >> 3) & 63;
    int t = (idx >> 9) & 7;
    int kt = idx >> 12;
    int k = kt * 32 + (l >> 4) * 8 + j;
    int c = t * 16 + (l & 15);
    w1pf[idx] = f2bf(W1[(size_t)k * F2 + c]);
  }
}

// ---------------- W2 prep ----------------
__global__ __launch_bounds__(256) void k_w2prep(const float* __restrict__ W2, ushort_t* __restrict__ w2p) {
  int idx = blockIdx.x * 256 + threadIdx.x;
  if (idx < 4 * 3 * 64 * 8) {
    int j = idx & 7;
    int rem = idx >> 3;
    int l = rem & 63;
    int g = rem >> 6;
    int t = g % 3, kt = g / 3;
    int colc = t * 16 + (l & 15);
    int k = kt * 32 + (l >> 4) * 8 + j;
    w2p[idx] = (colc < F3) ? f2bf(W2[(size_t)k * F3 + colc]) : (ushort_t)0;
  }
}

// ---------------- GEMM1 (MFMA, no LDS, 2 row-tiles/block): h0f8[N,128] = fp8(x @ W1) ----------------
// 128 rows per block: each B-fragment load feeds TWO MFMAs (2x arithmetic intensity on the B path)
__global__ __launch_bounds__(256) void k_gemm1(const float* __restrict__ x, const ushort_t* __restrict__ w1pf,
                                               uchar_t* __restrict__ h0f8, int N) {
  const int tid = threadIdx.x;
  const int lane = tid & 63;
  const int w = tid >> 6;
  const int r0 = blockIdx.x * 128;
  const int rowA = r0 + w * 16 + (lane & 15);
  const int rowB = rowA + 64;
  const int arA = (rowA < N) ? rowA : 0;
  const int arB = (rowB < N) ? rowB : 0;
  const int kg = (lane >> 4) * 8;
  const float* xrA = x + (size_t)arA * F1 + kg;
  const float* xrB = x + (size_t)arB * F1 + kg;

  f32x4 accA[8], accB[8];
#pragma unroll
  for (int t = 0; t < 8; ++t) {
    accA[t] = (f32x4){0.f, 0.f, 0.f, 0.f};
    accB[t] = (f32x4){0.f, 0.f, 0.f, 0.f};
  }

#pragma unroll
  for (int kt = 0; kt < 8; ++kt) {
    f32x4 vA0 = *(const f32x4*)(xrA + kt * 32);
    f32x4 vA1 = *(const f32x4*)(xrA + kt * 32 + 4);
    f32x4 vB0 = *(const f32x4*)(xrB + kt * 32);
    f32x4 vB1 = *(const f32x4*)(xrB + kt * 32 + 4);
    bf16x8 aA, aB;
    aA[0] = (short)f2bf(vA0.x); aA[1] = (short)f2bf(vA0.y);
    aA[2] = (short)f2bf(vA0.z); aA[3] = (short)f2bf(vA0.w);
    aA[4] = (short)f2bf(vA1.x); aA[5] = (short)f2bf(vA1.y);
    aA[6] = (short)f2bf(vA1.z); aA[7] = (short)f2bf(vA1.w);
    aB[0] = (short)f2bf(vB0.x); aB[1] = (short)f2bf(vB0.y);
    aB[2] = (short)f2bf(vB0.z); aB[3] = (short)f2bf(vB0.w);
    aB[4] = (short)f2bf(vB1.x); aB[5] = (short)f2bf(vB1.y);
    aB[6] = (short)f2bf(vB1.z); aB[7] = (short)f2bf(vB1.w);
#pragma unroll
    for (int t = 0; t < 8; ++t) {
      bf16x8 b = *(const bf16x8*)(w1pf + (size_t)(((kt * 8 + t) * 64) + lane) * 8);
      accA[t] = __builtin_amdgcn_mfma_f32_16x16x32_bf16(aA, b, accA[t], 0, 0, 0);
      accB[t] = __builtin_amdgcn_mfma_f32_16x16x32_bf16(aB, b, accB[t], 0, 0, 0);
    }
  }

  // C/D layout (HW-verified): col = lane&15, row = (lane>>4)*4 + j
#pragma unroll
  for (int t = 0; t < 8; ++t) {
    int gc = t * 16 + (lane & 15);
#pragma unroll
    for (int j = 0; j < 4; ++j) {
      int grA = r0 + w * 16 + (lane >> 4) * 4 + j;
      int grB = grA + 64;
      if (grA < N) h0f8[(size_t)grA * F2 + gc] = f2fp8(accA[t][j]);
      if (grB < N) h0f8[(size_t)grB * F2 + gc] = f2fp8(accB[t][j]);
    }
  }
}

// ---------------- SpMM1: 2 edges per gather instruction (32 dword-lanes each) ----------------
__global__ __launch_bounds__(256) void k_spmm1(const int* __restrict__ ip, const long long* __restrict__ epk,
                                               const uchar_t* __restrict__ h0f8,
                                               const float* __restrict__ b1, ushort_t* __restrict__ hbf) {
  int node = blockIdx.x * 4 + (threadIdx.x >> 6);
  int lane = threadIdx.x & 63;
  int e0 = __builtin_amdgcn_readfirstlane(ip[node]);
  int e1 = __builtin_amdgcn_readfirstlane(ip[node + 1]);
  const uint_t* hb = (const uint_t*)h0f8;   // row = 32 dwords
  const int half = lane >> 5;
  const int d = lane & 31;
  float a0x = 0.f, a0y = 0.f, a0z = 0.f, a0w = 0.f;
  float a1x = 0.f, a1y = 0.f, a1z = 0.f, a1w = 0.f;
  float a2x = 0.f, a2y = 0.f, a2z = 0.f, a2w = 0.f;
  float a3x = 0.f, a3y = 0.f, a3z = 0.f, a3w = 0.f;
  for (int e = e0; e < e1; e += 8) {
    int i1 = e1 - 1;
    long long p0 = nt_ld_rec(&epk[(e + 0 < e1) ? e + 0 : i1]);
    long long p1 = nt_ld_rec(&epk[(e + 1 < e1) ? e + 1 : i1]);
    long long p2 = nt_ld_rec(&epk[(e + 2 < e1) ? e + 2 : i1]);
    long long p3 = nt_ld_rec(&epk[(e + 3 < e1) ? e + 3 : i1]);
    long long p4 = nt_ld_rec(&epk[(e + 4 < e1) ? e + 4 : i1]);
    long long p5 = nt_ld_rec(&epk[(e + 5 < e1) ? e + 5 : i1]);
    long long p6 = nt_ld_rec(&epk[(e + 6 < e1) ? e + 6 : i1]);
    long long p7 = nt_ld_rec(&epk[(e + 7 < e1) ? e + 7 : i1]);
    int c0 = half ? rec_col(p1) : rec_col(p0);
    int c1 = half ? rec_col(p3) : rec_col(p2);
    int c2 = half ? rec_col(p5) : rec_col(p4);
    int c3 = half ? rec_col(p7) : rec_col(p6);
    uint_t u0 = hb[(size_t)c0 * 32 + d];
    uint_t u1 = hb[(size_t)c1 * 32 + d];
    uint_t u2 = hb[(size_t)c2 * 32 + d];
    uint_t u3 = hb[(size_t)c3 * 32 + d];
    float w0 = (e + 0 + half < e1) ? (half ? rec_w(p1) : rec_w(p0)) : 0.f;
    float w1 = (e + 2 + half < e1) ? (half ? rec_w(p3) : rec_w(p2)) : 0.f;
    float w2 = (e + 4 + half < e1) ? (half ? rec_w(p5) : rec_w(p4)) : 0.f;
    float w3 = (e + 6 + half < e1) ? (half ? rec_w(p7) : rec_w(p6)) : 0.f;
    f32x2 l0 = fp8lo(u0), h0 = fp8hi(u0);
    f32x2 l1 = fp8lo(u1), h1 = fp8hi(u1);
    f32x2 l2 = fp8lo(u2), h2 = fp8hi(u2);
    f32x2 l3 = fp8lo(u3), h3 = fp8hi(u3);
    a0x = fmaf(w0, l0.x, a0x); a0y = fmaf(w0, l0.y, a0y); a0z = fmaf(w0, h0.x, a0z); a0w = fmaf(w0, h0.y, a0w);
    a1x = fmaf(w1, l1.x, a1x); a1y = fmaf(w1, l1.y, a1y); a1z = fmaf(w1, h1.x, a1z); a1w = fmaf(w1, h1.y, a1w);
    a2x = fmaf(w2, l2.x, a2x); a2y = fmaf(w2, l2.y, a2y); a2z = fmaf(w2, h2.x, a2z); a2w = fmaf(w2, h2.y, a2w);
    a3x = fmaf(w3, l3.x, a3x); a3y = fmaf(w3, l3.y, a3y); a3z = fmaf(w3, h3.x, a3z); a3w = fmaf(w3, h3.y, a3w);
  }
  float sx = (a0x + a1x) + (a2x + a3x);
  float sy = (a0y + a1y) + (a2y + a3y);
  float sz = (a0z + a1z) + (a2z + a3z);
  float sw = (a0w + a1w) + (a2w + a3w);
  sx += __shfl_xor(sx, 32);
  sy += __shfl_xor(sy, 32);
  sz += __shfl_xor(sz, 32);
  sw += __shfl_xor(sw, 32);
  float4 bb = *(const float4*)(b1 + d * 4);
  unsigned long long rr =
      (unsigned long long)f2bf(fmaxf(sx + bb.x, 0.f)) |
      ((unsigned long long)f2bf(fmaxf(sy + bb.y, 0.f)) << 16) |
      ((unsigned long long)f2bf(fmaxf(sz + bb.z, 0.f)) << 32) |
      ((unsigned long long)f2bf(fmaxf(sw + bb.w, 0.f)) << 48);
  if (lane < 32)
    __builtin_nontemporal_store(rr, (unsigned long long*)(hbf + (size_t)node * F2 + d * 4));
}

// ---------------- GEMM2 (MFMA, no LDS): h2f8[N,64B] = fp8(h @ W2) ----------------
__global__ __launch_bounds__(256) void k_gemm2(const ushort_t* __restrict__ hbf, const ushort_t* __restrict__ w2p,
                                               uchar_t* __restrict__ h2f8, int N) {
  const int tid = threadIdx.x;
  const int lane = tid & 63;
  const int w = tid >> 6;
  const int r0 = blockIdx.x * 64;
  const int arow = r0 + w * 16 + (lane & 15);
  const int ar = (arow < N) ? arow : 0;
  const int kg = (lane >> 4) * 8;

  bf16x8 a[4];
#pragma unroll
  for (int kt = 0; kt < 4; ++kt)
    a[kt] = *(const bf16x8*)(hbf + (size_t)ar * F2 + kt * 32 + kg);

  f32x4 acc[3];
#pragma unroll
  for (int t = 0; t < 3; ++t) acc[t] = (f32x4){0.f, 0.f, 0.f, 0.f};

#pragma unroll
  for (int kt = 0; kt < 4; ++kt) {
#pragma unroll
    for (int t = 0; t < 3; ++t) {
      bf16x8 b = *(const bf16x8*)(w2p + (size_t)(((kt * 3 + t) * 64) + lane) * 8);
      acc[t] = __builtin_amdgcn_mfma_f32_16x16x32_bf16(a[kt], b, acc[t], 0, 0, 0);
    }
  }

#pragma unroll
  for (int t = 0; t < 3; ++t) {
    int gc = t * 16 + (lane & 15);
    if (gc < F3) {
#pragma unroll
      for (int j = 0; j < 4; ++j) {
        int gr = r0 + w * 16 + (lane >> 4) * 4 + j;
        if (gr < N) h2f8[(size_t)gr * H2S + gc] = f2fp8(acc[t][j]);
      }
    }
  }
  for (int idx = tid; idx < 64 * 24; idx += 256) {
    int row = idx / 24, pc = F3 + idx % 24;
    int gr = r0 + row;
    if (gr < N) h2f8[(size_t)gr * H2S + pc] = 0;
  }
}

// ---------------- SpMM2 + lsm: 4 edges per gather instruction (16 dword-lanes each) ----------------
__global__ __launch_bounds__(256) void k_spmm2lsm(const int* __restrict__ ip, const long long* __restrict__ epk,
                                                  const uchar_t* __restrict__ h2f8,
                                                  const float* __restrict__ b2, float* __restrict__ out) {
  int node = blockIdx.x * 4 + (threadIdx.x >> 6);
  int lane = threadIdx.x & 63;
  int e0 = __builtin_amdgcn_readfirstlane(ip[node]);
  int e1 = __builtin_amdgcn_readfirstlane(ip[node + 1]);
  const uint_t* hb = (const uint_t*)h2f8;
  const int slot = lane >> 4;
  const int d = lane & 15;
  float aAx = 0.f, aAy = 0.f, aAz = 0.f, aAw = 0.f;
  float aBx = 0.f, aBy = 0.f, aBz = 0.f, aBw = 0.f;
  for (int e = e0; e < e1; e += 8) {
    int i1 = e1 - 1;
    long long p0 = nt_ld_rec(&epk[(e + 0 < e1) ? e + 0 : i1]);
    long long p1 = nt_ld_rec(&epk[(e + 1 < e1) ? e + 1 : i1]);
    long long p2 = nt_ld_rec(&epk[(e + 2 < e1) ? e + 2 : i1]);
    long long p3 = nt_ld_rec(&epk[(e + 3 < e1) ? e + 3 : i1]);
    long long p4 = nt_ld_rec(&epk[(e + 4 < e1) ? e + 4 : i1]);
    long long p5 = nt_ld_rec(&epk[(e + 5 < e1) ? e + 5 : i1]);
    long long p6 = nt_ld_rec(&epk[(e + 6 < e1) ? e + 6 : i1]);
    long long p7 = nt_ld_rec(&epk[(e + 7 < e1) ? e + 7 : i1]);
    long long qa = (slot < 2) ? (slot == 0 ? p0 : p1) : (slot == 2 ? p2 : p3);
    long long qb = (slot < 2) ? (slot == 0 ? p4 : p5) : (slot == 2 ? p6 : p7);
    uint_t uA = hb[(size_t)rec_col(qa) * 16 + d];
    uint_t uB = hb[(size_t)rec_col(qb) * 16 + d];
    float wA = (e + slot < e1) ? rec_w(qa) : 0.f;
    float wB = (e + 4 + slot < e1) ? rec_w(qb) : 0.f;
    f32x2 lA = fp8lo(uA), hA = fp8hi(uA);
    f32x2 lB = fp8lo(uB), hB = fp8hi(uB);
    aAx = fmaf(wA, lA.x, aAx); aAy = fmaf(wA, lA.y, aAy); aAz = fmaf(wA, hA.x, aAz); aAw = fmaf(wA, hA.y, aAw);
    aBx = fmaf(wB, lB.x, aBx); aBy = fmaf(wB, lB.y, aBy); aBz = fmaf(wB, hB.x, aBz); aBw = fmaf(wB, hB.y, aBw);
  }
  float sx = aAx + aBx, sy = aAy + aBy, sz = aAz + aBz, sw = aAw + aBw;
  sx += __shfl_xor(sx, 16); sx += __shfl_xor(sx, 32);
  sy += __shfl_xor(sy, 16); sy += __shfl_xor(sy, 32);
  sz += __shfl_xor(sz, 16); sz += __shfl_xor(sz, 32);
  sw += __shfl_xor(sw, 16); sw += __shfl_xor(sw, 32);
  float l0 = -INFINITY, l1 = -INFINITY, l2 = -INFINITY, l3 = -INFINITY;
  if (d < 10) {
    float4 bb = *(const float4*)(b2 + d * 4);
    l0 = sx + bb.x; l1 = sy + bb.y; l2 = sz + bb.z; l3 = sw + bb.w;
  }
  float m = fmaxf(fmaxf(l0, l1), fmaxf(l2, l3));
#pragma unroll
  for (int off = 1; off < 16; off <<= 1) m = fmaxf(m, __shfl_xor(m, off));
  float e0x = (d < 10) ? __expf(l0 - m) : 0.f;
  float e1x = (d < 10) ? __expf(l1 - m) : 0.f;
  float e2x = (d < 10) ? __expf(l2 - m) : 0.f;
  float e3x = (d < 10) ? __expf(l3 - m) : 0.f;
  float s = (e0x + e1x) + (e2x + e3x);
#pragma unroll
  for (int off = 1; off < 16; off <<= 1) s += __shfl_xor(s, off);
  float ls = __logf(s);
  if (d < 10) {
    f32x4 r;
    r[0] = l0 - m - ls; r[1] = l1 - m - ls; r[2] = l2 - m - ls; r[3] = l3 - m - ls;
    __builtin_nontemporal_store(r, (f32x4*)(out + (size_t)node * F3 + d * 4));
  }
}

extern "C" void kernel_launch(void* const* d_in, const int* in_sizes, int n_in,
                              void* d_out, int out_size, void* d_ws, size_t ws_size,
                              hipStream_t stream) {
  const float* x     = (const float*)d_in[0];
  const int* erow    = (const int*)d_in[1];
  const int* ecol_in = (const int*)d_in[2];
  const float* ew_in = (const float*)d_in[3];
  const float* W1    = (const float*)d_in[4];
  const float* b1    = (const float*)d_in[5];
  const float* W2    = (const float*)d_in[6];
  const float* b2    = (const float*)d_in[7];
  float* out = (float*)d_out;

  const int N = in_sizes[0] / F1;  // 100000
  const int E = in_sizes[1];       // 1600000

  const int G = (E + TPB - 1) / TPB;          // 196
  const int NBIN = (N + RPB - 1) >> RSH;      // 391
  const int M = NBIN * G;                     // 76636
  const int nb2 = (M + 1023) / 1024;          // 75

  uchar_t* region0 = (uchar_t*)d_ws;
  int2* epk2 = (int2*)d_ws;
  uchar_t* h0f8 = region0;
  uchar_t* h2f8 = region0;
  ushort_t* hbf = (ushort_t*)(region0 + (size_t)N * F2 * 2);
  int* ip = (int*)(hbf + (size_t)N * F2);
  int* cnt = ip + (N + 32);
  int* cntoff = cnt + M + 8;
  int* aux = cntoff + M + 64;
  int2* epk = (int2*)(aux + 128);
  ushort_t* w1pf = (ushort_t*)(epk + E);
  ushort_t* w2p = w1pf + 32768;

  hipLaunchKernelGGL(k_cnt, dim3(G), dim3(256), 0, stream, erow, cnt, E, G, NBIN);
  hipLaunchKernelGGL(k_scan1, dim3(nb2), dim3(256), 0, stream, cnt, cntoff, aux, M);
  hipLaunchKernelGGL(k_scan_aux, dim3(1), dim3(128), 0, stream, aux, nb2);
  hipLaunchKernelGGL(k_scan_add, dim3(nb2), dim3(256), 0, stream, cntoff, aux, M, E);
  hipLaunchKernelGGL(k_scatter1, dim3(G), dim3(256), 0, stream, erow, ecol_in, ew_in, cntoff, epk2, E, G, NBIN);
  hipLaunchKernelGGL(k_binsort, dim3(NBIN), dim3(256), 0, stream, cntoff, epk2, ip, epk, G, NBIN, N, E);
  hipLaunchKernelGGL(k_w1prep, dim3(128), dim3(256), 0, stream, W1, w1pf);
  hipLaunchKernelGGL(k_w2prep, dim3((4 * 3 * 64 * 8 + 255) / 256), dim3(256), 0, stream, W2, w2p);
  hipLaunchKernelGGL(k_gemm1, dim3((N + 127) / 128), dim3(256), 0, stream, x, w1pf, h0f8, N);
  hipLaunchKernelGGL(k_spmm1, dim3(N / 4), dim3(256), 0, stream, ip, (const long long*)epk, h0f8, b1, hbf);
  hipLaunchKernelGGL(k_gemm2, dim3((N + 63) / 64), dim3(256), 0, stream, hbf, w2p, h2f8, N);
  hipLaunchKernelGGL(k_spmm2lsm, dim3(N / 4), dim3(256), 0, stream, ip, (const long long*)epk, h2f8, b2, out);
}

// Round 18
// 198.746 us; speedup vs baseline: 1.0453x; 1.0453x over previous
//
#include <hip/hip_runtime.h>
#include <math.h>

#define F1 256
#define F2 128
#define F3 40
#define H2S 64    // h2 fp8 row stride in bytes (16 dwords; 10 valid + zero pad)
#define RPB 256
#define RSH 8
#define TPB 8192

typedef unsigned short ushort_t;
typedef unsigned char uchar_t;
typedef unsigned int uint_t;
typedef __attribute__((ext_vector_type(8))) short bf16x8;
typedef __attribute__((ext_vector_type(4))) float f32x4;
typedef __attribute__((ext_vector_type(2))) float f32x2;

__device__ inline ushort_t f2bf(float f) {
  unsigned u = __builtin_bit_cast(unsigned, f);
  u += 0x7FFF + ((u >> 16) & 1);
  return (ushort_t)(u >> 16);
}
__device__ inline float bf2f(ushort_t b) {
  unsigned u = ((unsigned)b) << 16;
  return __builtin_bit_cast(float, u);
}
__device__ inline float i2f(int b) { return __builtin_bit_cast(float, b); }
__device__ inline uchar_t f2fp8(float f) {
  return (uchar_t)(__builtin_amdgcn_cvt_pk_fp8_f32(f, 0.f, 0, false) & 0xff);
}
__device__ inline f32x2 fp8lo(unsigned u) { return __builtin_amdgcn_cvt_pk_f32_fp8(u, false); }
__device__ inline f32x2 fp8hi(unsigned u) { return __builtin_amdgcn_cvt_pk_f32_fp8(u, true); }
__device__ inline long long nt_ld_rec(const long long* p) {
  return __builtin_nontemporal_load(p);
}
__device__ inline int rec_col(long long r) { return (int)(unsigned)(r & 0xffffffffll); }
__device__ inline float rec_w(long long r) { return i2f((int)(unsigned)(((unsigned long long)r) >> 32)); }

// ---------------- CSR build: 2-level counting sort ----------------

__global__ __launch_bounds__(256) void k_cnt(const int* __restrict__ row, int* __restrict__ cnt,
                                             int E, int G, int NBIN) {
  __shared__ int h[400];
  int tid = threadIdx.x, blk = blockIdx.x;
  for (int i = tid; i < NBIN; i += 256) h[i] = 0;
  __syncthreads();
  int base = blk * TPB, lim = min(base + TPB, E);
  for (int i = base + tid; i < lim; i += 256) atomicAdd(&h[row[i] >> RSH], 1);
  __syncthreads();
  for (int i = tid; i < NBIN; i += 256) cnt[i * G + blk] = h[i];
}

__global__ __launch_bounds__(256) void k_scan1(const int* __restrict__ in, int* __restrict__ out,
                                               int* __restrict__ aux, int n) {
  __shared__ int lds[256];
  int tid = threadIdx.x;
  int base = blockIdx.x * 1024 + tid * 4;
  int v0 = 0, v1 = 0, v2 = 0, v3 = 0;
  if (base + 0 < n) v0 = in[base + 0];
  if (base + 1 < n) v1 = in[base + 1];
  if (base + 2 < n) v2 = in[base + 2];
  if (base + 3 < n) v3 = in[base + 3];
  int s = v0 + v1 + v2 + v3;
  lds[tid] = s;
  __syncthreads();
  for (int off = 1; off < 256; off <<= 1) {
    int t = (tid >= off) ? lds[tid - off] : 0;
    __syncthreads();
    lds[tid] += t;
    __syncthreads();
  }
  int excl = (tid > 0) ? lds[tid - 1] : 0;
  if (tid == 255) aux[blockIdx.x] = lds[255];
  if (base + 0 < n) out[base + 0] = excl;
  if (base + 1 < n) out[base + 1] = excl + v0;
  if (base + 2 < n) out[base + 2] = excl + v0 + v1;
  if (base + 3 < n) out[base + 3] = excl + v0 + v1 + v2;
}

__global__ __launch_bounds__(128) void k_scan_aux(int* __restrict__ aux, int nb) {
  __shared__ int lds[128];
  int tid = threadIdx.x;
  int v = (tid < nb) ? aux[tid] : 0;
  lds[tid] = v;
  __syncthreads();
  for (int off = 1; off < 128; off <<= 1) {
    int t = (tid >= off) ? lds[tid - off] : 0;
    __syncthreads();
    lds[tid] += t;
    __syncthreads();
  }
  int excl = (tid > 0) ? lds[tid - 1] : 0;
  if (tid < nb) aux[tid] = excl;
}

__global__ __launch_bounds__(256) void k_scan_add(int* __restrict__ out, const int* __restrict__ aux,
                                                  int n, int E) {
  int add = aux[blockIdx.x];
  int base = blockIdx.x * 1024 + threadIdx.x * 4;
#pragma unroll
  for (int i = 0; i < 4; i++)
    if (base + i < n) out[base + i] += add;
  if (blockIdx.x == 0 && threadIdx.x == 0) out[n] = E;
}

__global__ __launch_bounds__(256) void k_scatter1(const int* __restrict__ row, const int* __restrict__ col,
                                                  const float* __restrict__ w, const int* __restrict__ cntoff,
                                                  int2* __restrict__ epk2, int E, int G, int NBIN) {
  __shared__ int cur[400];
  int tid = threadIdx.x, blk = blockIdx.x;
  for (int i = tid; i < NBIN; i += 256) cur[i] = cntoff[i * G + blk];
  __syncthreads();
  int base = blk * TPB, lim = min(base + TPB, E);
  for (int i = base + tid; i < lim; i += 256) {
    int r = row[i];
    int pos = atomicAdd(&cur[r >> RSH], 1);
    epk2[pos] = make_int2(((r & (RPB - 1)) << 17) | col[i], __builtin_bit_cast(int, w[i]));
  }
}

__global__ __launch_bounds__(256) void k_binsort(const int* __restrict__ cntoff, const int2* __restrict__ epk2,
                                                 int* __restrict__ ip, int2* __restrict__ epk,
                                                 int G, int NBIN, int N, int E) {
  __shared__ int sc[256], cur[256];
  int tid = threadIdx.x, b = blockIdx.x;
  int s = cntoff[b * G], eend = cntoff[(b + 1) * G];
  cur[tid] = 0;
  __syncthreads();
  for (int i = s + tid; i < eend; i += 256) atomicAdd(&cur[epk2[i].x >> 17], 1);
  __syncthreads();
  int d = cur[tid];
  sc[tid] = d;
  __syncthreads();
  for (int o = 1; o < 256; o <<= 1) {
    int t = (tid >= o) ? sc[tid - o] : 0;
    __syncthreads();
    sc[tid] += t;
    __syncthreads();
  }
  int excl = (tid > 0) ? sc[tid - 1] : 0;
  __syncthreads();
  cur[tid] = excl;
  int gr = (b << RSH) + tid;
  if (gr <= N) ip[gr] = s + excl;
  if (b == 0 && tid == 0) ip[N] = E;
  __syncthreads();
  for (int i = s + tid; i < eend; i += 256) {
    int2 rec = epk2[i];
    int local = rec.x >> 17, c = rec.x & 0x1FFFF;
    int p = s + atomicAdd(&cur[local], 1);
    epk[p] = make_int2(c, rec.y);
  }
}

// ---------------- W1 prep: fp32 [256][128] -> [th 2][kt 8][tl 4][lane 64][8] (two 32KB halves) ----------------
__global__ __launch_bounds__(256) void k_w1prep(const float* __restrict__ W1, ushort_t* __restrict__ w1pf) {
  int idx = blockIdx.x * 256 + threadIdx.x;
  if (idx < 2 * 8 * 4 * 64 * 8) {
    int j = idx & 7;
    int l = (idx >> 3) & 63;
    int g = idx >> 9;          // 0..63
    int tl = g & 3;
    int kt = (g >> 2) & 7;
    int th = g >> 5;
    int t = th * 4 + tl;
    int k = kt * 32 + (l >> 4) * 8 + j;
    int c = t * 16 + (l & 15);
    w1pf[idx] = f2bf(W1[(size_t)k * F2 + c]);
  }
}

// ---------------- W2 prep ----------------
__global__ __launch_bounds__(256) void k_w2prep(const float* __restrict__ W2, ushort_t* __restrict__ w2p) {
  int idx = blockIdx.x * 256 + threadIdx.x;
  if (idx < 4 * 3 * 64 * 8) {
    int j = idx & 7;
    int rem = idx >> 3;
    int l = rem & 63;
    int g = rem >> 6;
    int t = g % 3, kt = g / 3;
    int colc = t * 16 + (l & 15);
    int k = kt * 32 + (l >> 4) * 8 + j;
    w2p[idx] = (colc < F3) ? f2bf(W2[(size_t)k * F3 + colc]) : (ushort_t)0;
  }
}

// ---------------- GEMM1 (MFMA, B from LDS, x direct): h0f8[N,128] = fp8(x @ W1) ----------------
// 64 rows/block, 4 waves. B served from LDS (20cy) instead of L2 (~250cy); x loads 16-deep MLP.
// Two col-halves of 32KB each -> 5 blocks/CU LDS occupancy.
__global__ __launch_bounds__(256) void k_gemm1(const float* __restrict__ x, const ushort_t* __restrict__ w1pf,
                                               uchar_t* __restrict__ h0f8, int N) {
  __shared__ uint4 wlds[2048];   // 32KB
  const int tid = threadIdx.x;
  const int lane = tid & 63;
  const int w = tid >> 6;
  const int r0 = blockIdx.x * 64;
  const int arow = r0 + w * 16 + (lane & 15);
  const int ar = (arow < N) ? arow : 0;
  const int kg = (lane >> 4) * 8;
  const float* xr = x + (size_t)ar * F1 + kg;
  const ushort_t* wb = (const ushort_t*)wlds;

  // phase 1: issue all 16 independent x loads
  f32x4 xv[16];
#pragma unroll
  for (int kt = 0; kt < 8; ++kt) {
    xv[2 * kt]     = *(const f32x4*)(xr + kt * 32);
    xv[2 * kt + 1] = *(const f32x4*)(xr + kt * 32 + 4);
  }

  // stage half 0 of W1 fragments (32KB, coalesced, conflict-free)
  {
    const uint4* src = (const uint4*)w1pf;
    for (int o = tid; o < 2048; o += 256) wlds[o] = src[o];
  }

  // convert x to bf16 A-fragments (overlaps staging)
  bf16x8 a[8];
#pragma unroll
  for (int kt = 0; kt < 8; ++kt) {
    f32x4 v0 = xv[2 * kt], v1 = xv[2 * kt + 1];
    a[kt][0] = (short)f2bf(v0.x); a[kt][1] = (short)f2bf(v0.y);
    a[kt][2] = (short)f2bf(v0.z); a[kt][3] = (short)f2bf(v0.w);
    a[kt][4] = (short)f2bf(v1.x); a[kt][5] = (short)f2bf(v1.y);
    a[kt][6] = (short)f2bf(v1.z); a[kt][7] = (short)f2bf(v1.w);
  }
  __syncthreads();

  const int orow = r0 + w * 16 + (lane >> 4) * 4;  // +j for output rows

#pragma unroll
  for (int th = 0; th < 2; ++th) {
    f32x4 acc[4];
#pragma unroll
    for (int tl = 0; tl < 4; ++tl) acc[tl] = (f32x4){0.f, 0.f, 0.f, 0.f};
#pragma unroll
    for (int kt = 0; kt < 8; ++kt) {
#pragma unroll
      for (int tl = 0; tl < 4; ++tl) {
        bf16x8 b = *(const bf16x8*)&wb[(size_t)((kt * 4 + tl) * 64 + lane) * 8];
        acc[tl] = __builtin_amdgcn_mfma_f32_16x16x32_bf16(a[kt], b, acc[tl], 0, 0, 0);
      }
    }
    // store this half's columns: t = th*4 + tl, col = t*16 + (lane&15)
#pragma unroll
    for (int tl = 0; tl < 4; ++tl) {
      int gc = (th * 4 + tl) * 16 + (lane & 15);
#pragma unroll
      for (int j = 0; j < 4; ++j) {
        int gr = orow + j;
        if (gr < N) h0f8[(size_t)gr * F2 + gc] = f2fp8(acc[tl][j]);
      }
    }
    if (th == 0) {
      __syncthreads();  // all waves done reading half 0
      const uint4* src = (const uint4*)w1pf + 2048;
      for (int o = tid; o < 2048; o += 256) wlds[o] = src[o];
      __syncthreads();  // half 1 staged
    }
  }
}

// ---------------- SpMM1: 2 edges per gather instruction (32 dword-lanes each) ----------------
__global__ __launch_bounds__(256) void k_spmm1(const int* __restrict__ ip, const long long* __restrict__ epk,
                                               const uchar_t* __restrict__ h0f8,
                                               const float* __restrict__ b1, ushort_t* __restrict__ hbf) {
  int node = blockIdx.x * 4 + (threadIdx.x >> 6);
  int lane = threadIdx.x & 63;
  int e0 = __builtin_amdgcn_readfirstlane(ip[node]);
  int e1 = __builtin_amdgcn_readfirstlane(ip[node + 1]);
  const uint_t* hb = (const uint_t*)h0f8;   // row = 32 dwords
  const int half = lane >> 5;
  const int d = lane & 31;
  float a0x = 0.f, a0y = 0.f, a0z = 0.f, a0w = 0.f;
  float a1x = 0.f, a1y = 0.f, a1z = 0.f, a1w = 0.f;
  float a2x = 0.f, a2y = 0.f, a2z = 0.f, a2w = 0.f;
  float a3x = 0.f, a3y = 0.f, a3z = 0.f, a3w = 0.f;
  for (int e = e0; e < e1; e += 8) {
    int i1 = e1 - 1;
    long long p0 = nt_ld_rec(&epk[(e + 0 < e1) ? e + 0 : i1]);
    long long p1 = nt_ld_rec(&epk[(e + 1 < e1) ? e + 1 : i1]);
    long long p2 = nt_ld_rec(&epk[(e + 2 < e1) ? e + 2 : i1]);
    long long p3 = nt_ld_rec(&epk[(e + 3 < e1) ? e + 3 : i1]);
    long long p4 = nt_ld_rec(&epk[(e + 4 < e1) ? e + 4 : i1]);
    long long p5 = nt_ld_rec(&epk[(e + 5 < e1) ? e + 5 : i1]);
    long long p6 = nt_ld_rec(&epk[(e + 6 < e1) ? e + 6 : i1]);
    long long p7 = nt_ld_rec(&epk[(e + 7 < e1) ? e + 7 : i1]);
    int c0 = half ? rec_col(p1) : rec_col(p0);
    int c1 = half ? rec_col(p3) : rec_col(p2);
    int c2 = half ? rec_col(p5) : rec_col(p4);
    int c3 = half ? rec_col(p7) : rec_col(p6);
    uint_t u0 = hb[(size_t)c0 * 32 + d];
    uint_t u1 = hb[(size_t)c1 * 32 + d];
    uint_t u2 = hb[(size_t)c2 * 32 + d];
    uint_t u3 = hb[(size_t)c3 * 32 + d];
    float w0 = (e + 0 + half < e1) ? (half ? rec_w(p1) : rec_w(p0)) : 0.f;
    float w1 = (e + 2 + half < e1) ? (half ? rec_w(p3) : rec_w(p2)) : 0.f;
    float w2 = (e + 4 + half < e1) ? (half ? rec_w(p5) : rec_w(p4)) : 0.f;
    float w3 = (e + 6 + half < e1) ? (half ? rec_w(p7) : rec_w(p6)) : 0.f;
    f32x2 l0 = fp8lo(u0), h0 = fp8hi(u0);
    f32x2 l1 = fp8lo(u1), h1 = fp8hi(u1);
    f32x2 l2 = fp8lo(u2), h2 = fp8hi(u2);
    f32x2 l3 = fp8lo(u3), h3 = fp8hi(u3);
    a0x = fmaf(w0, l0.x, a0x); a0y = fmaf(w0, l0.y, a0y); a0z = fmaf(w0, h0.x, a0z); a0w = fmaf(w0, h0.y, a0w);
    a1x = fmaf(w1, l1.x, a1x); a1y = fmaf(w1, l1.y, a1y); a1z = fmaf(w1, h1.x, a1z); a1w = fmaf(w1, h1.y, a1w);
    a2x = fmaf(w2, l2.x, a2x); a2y = fmaf(w2, l2.y, a2y); a2z = fmaf(w2, h2.x, a2z); a2w = fmaf(w2, h2.y, a2w);
    a3x = fmaf(w3, l3.x, a3x); a3y = fmaf(w3, l3.y, a3y); a3z = fmaf(w3, h3.x, a3z); a3w = fmaf(w3, h3.y, a3w);
  }
  float sx = (a0x + a1x) + (a2x + a3x);
  float sy = (a0y + a1y) + (a2y + a3y);
  float sz = (a0z + a1z) + (a2z + a3z);
  float sw = (a0w + a1w) + (a2w + a3w);
  sx += __shfl_xor(sx, 32);
  sy += __shfl_xor(sy, 32);
  sz += __shfl_xor(sz, 32);
  sw += __shfl_xor(sw, 32);
  float4 bb = *(const float4*)(b1 + d * 4);
  unsigned long long rr =
      (unsigned long long)f2bf(fmaxf(sx + bb.x, 0.f)) |
      ((unsigned long long)f2bf(fmaxf(sy + bb.y, 0.f)) << 16) |
      ((unsigned long long)f2bf(fmaxf(sz + bb.z, 0.f)) << 32) |
      ((unsigned long long)f2bf(fmaxf(sw + bb.w, 0.f)) << 48);
  if (lane < 32)
    __builtin_nontemporal_store(rr, (unsigned long long*)(hbf + (size_t)node * F2 + d * 4));
}

// ---------------- GEMM2 (MFMA, no LDS): h2f8[N,64B] = fp8(h @ W2) ----------------
__global__ __launch_bounds__(256) void k_gemm2(const ushort_t* __restrict__ hbf, const ushort_t* __restrict__ w2p,
                                               uchar_t* __restrict__ h2f8, int N) {
  const int tid = threadIdx.x;
  const int lane = tid & 63;
  const int w = tid >> 6;
  const int r0 = blockIdx.x * 64;
  const int arow = r0 + w * 16 + (lane & 15);
  const int ar = (arow < N) ? arow : 0;
  const int kg = (lane >> 4) * 8;

  bf16x8 a[4];
#pragma unroll
  for (int kt = 0; kt < 4; ++kt)
    a[kt] = *(const bf16x8*)(hbf + (size_t)ar * F2 + kt * 32 + kg);

  f32x4 acc[3];
#pragma unroll
  for (int t = 0; t < 3; ++t) acc[t] = (f32x4){0.f, 0.f, 0.f, 0.f};

#pragma unroll
  for (int kt = 0; kt < 4; ++kt) {
#pragma unroll
    for (int t = 0; t < 3; ++t) {
      bf16x8 b = *(const bf16x8*)(w2p + (size_t)(((kt * 3 + t) * 64) + lane) * 8);
      acc[t] = __builtin_amdgcn_mfma_f32_16x16x32_bf16(a[kt], b, acc[t], 0, 0, 0);
    }
  }

#pragma unroll
  for (int t = 0; t < 3; ++t) {
    int gc = t * 16 + (lane & 15);
    if (gc < F3) {
#pragma unroll
      for (int j = 0; j < 4; ++j) {
        int gr = r0 + w * 16 + (lane >> 4) * 4 + j;
        if (gr < N) h2f8[(size_t)gr * H2S + gc] = f2fp8(acc[t][j]);
      }
    }
  }
  for (int idx = tid; idx < 64 * 24; idx += 256) {
    int row = idx / 24, pc = F3 + idx % 24;
    int gr = r0 + row;
    if (gr < N) h2f8[(size_t)gr * H2S + pc] = 0;
  }
}

// ---------------- SpMM2 + lsm: 4 edges per gather instruction (16 dword-lanes each) ----------------
__global__ __launch_bounds__(256) void k_spmm2lsm(const int* __restrict__ ip, const long long* __restrict__ epk,
                                                  const uchar_t* __restrict__ h2f8,
                                                  const float* __restrict__ b2, float* __restrict__ out) {
  int node = blockIdx.x * 4 + (threadIdx.x >> 6);
  int lane = threadIdx.x & 63;
  int e0 = __builtin_amdgcn_readfirstlane(ip[node]);
  int e1 = __builtin_amdgcn_readfirstlane(ip[node + 1]);
  const uint_t* hb = (const uint_t*)h2f8;
  const int slot = lane >> 4;
  const int d = lane & 15;
  float aAx = 0.f, aAy = 0.f, aAz = 0.f, aAw = 0.f;
  float aBx = 0.f, aBy = 0.f, aBz = 0.f, aBw = 0.f;
  for (int e = e0; e < e1; e += 8) {
    int i1 = e1 - 1;
    long long p0 = nt_ld_rec(&epk[(e + 0 < e1) ? e + 0 : i1]);
    long long p1 = nt_ld_rec(&epk[(e + 1 < e1) ? e + 1 : i1]);
    long long p2 = nt_ld_rec(&epk[(e + 2 < e1) ? e + 2 : i1]);
    long long p3 = nt_ld_rec(&epk[(e + 3 < e1) ? e + 3 : i1]);
    long long p4 = nt_ld_rec(&epk[(e + 4 < e1) ? e + 4 : i1]);
    long long p5 = nt_ld_rec(&epk[(e + 5 < e1) ? e + 5 : i1]);
    long long p6 = nt_ld_rec(&epk[(e + 6 < e1) ? e + 6 : i1]);
    long long p7 = nt_ld_rec(&epk[(e + 7 < e1) ? e + 7 : i1]);
    long long qa = (slot < 2) ? (slot == 0 ? p0 : p1) : (slot == 2 ? p2 : p3);
    long long qb = (slot < 2) ? (slot == 0 ? p4 : p5) : (slot == 2 ? p6 : p7);
    uint_t uA = hb[(size_t)rec_col(qa) * 16 + d];
    uint_t uB = hb[(size_t)rec_col(qb) * 16 + d];
    float wA = (e + slot < e1) ? rec_w(qa) : 0.f;
    float wB = (e + 4 + slot < e1) ? rec_w(qb) : 0.f;
    f32x2 lA = fp8lo(uA), hA = fp8hi(uA);
    f32x2 lB = fp8lo(uB), hB = fp8hi(uB);
    aAx = fmaf(wA, lA.x, aAx); aAy = fmaf(wA, lA.y, aAy); aAz = fmaf(wA, hA.x, aAz); aAw = fmaf(wA, hA.y, aAw);
    aBx = fmaf(wB, lB.x, aBx); aBy = fmaf(wB, lB.y, aBy); aBz = fmaf(wB, hB.x, aBz); aBw = fmaf(wB, hB.y, aBw);
  }
  float sx = aAx + aBx, sy = aAy + aBy, sz = aAz + aBz, sw = aAw + aBw;
  sx += __shfl_xor(sx, 16); sx += __shfl_xor(sx, 32);
  sy += __shfl_xor(sy, 16); sy += __shfl_xor(sy, 32);
  sz += __shfl_xor(sz, 16); sz += __shfl_xor(sz, 32);
  sw += __shfl_xor(sw, 16); sw += __shfl_xor(sw, 32);
  float l0 = -INFINITY, l1 = -INFINITY, l2 = -INFINITY, l3 = -INFINITY;
  if (d < 10) {
    float4 bb = *(const float4*)(b2 + d * 4);
    l0 = sx + bb.x; l1 = sy + bb.y; l2 = sz + bb.z; l3 = sw + bb.w;
  }
  float m = fmaxf(fmaxf(l0, l1), fmaxf(l2, l3));
#pragma unroll
  for (int off = 1; off < 16; off <<= 1) m = fmaxf(m, __shfl_xor(m, off));
  float e0x = (d < 10) ? __expf(l0 - m) : 0.f;
  float e1x = (d < 10) ? __expf(l1 - m) : 0.f;
  float e2x = (d < 10) ? __expf(l2 - m) : 0.f;
  float e3x = (d < 10) ? __expf(l3 - m) : 0.f;
  float s = (e0x + e1x) + (e2x + e3x);
#pragma unroll
  for (int off = 1; off < 16; off <<= 1) s += __shfl_xor(s, off);
  float ls = __logf(s);
  if (d < 10) {
    f32x4 r;
    r[0] = l0 - m - ls; r[1] = l1 - m - ls; r[2] = l2 - m - ls; r[3] = l3 - m - ls;
    __builtin_nontemporal_store(r, (f32x4*)(out + (size_t)node * F3 + d * 4));
  }
}

extern "C" void kernel_launch(void* const* d_in, const int* in_sizes, int n_in,
                              void* d_out, int out_size, void* d_ws, size_t ws_size,
                              hipStream_t stream) {
  const float* x     = (const float*)d_in[0];
  const int* erow    = (const int*)d_in[1];
  const int* ecol_in = (const int*)d_in[2];
  const float* ew_in = (const float*)d_in[3];
  const float* W1    = (const float*)d_in[4];
  const float* b1    = (const float*)d_in[5];
  const float* W2    = (const float*)d_in[6];
  const float* b2    = (const float*)d_in[7];
  float* out = (float*)d_out;

  const int N = in_sizes[0] / F1;  // 100000
  const int E = in_sizes[1];       // 1600000

  const int G = (E + TPB - 1) / TPB;          // 196
  const int NBIN = (N + RPB - 1) >> RSH;      // 391
  const int M = NBIN * G;                     // 76636
  const int nb2 = (M + 1023) / 1024;          // 75

  uchar_t* region0 = (uchar_t*)d_ws;
  int2* epk2 = (int2*)d_ws;
  uchar_t* h0f8 = region0;
  uchar_t* h2f8 = region0;
  ushort_t* hbf = (ushort_t*)(region0 + (size_t)N * F2 * 2);
  int* ip = (int*)(hbf + (size_t)N * F2);
  int* cnt = ip + (N + 32);
  int* cntoff = cnt + M + 8;
  int* aux = cntoff + M + 64;
  int2* epk = (int2*)(aux + 128);
  ushort_t* w1pf = (ushort_t*)(epk + E);
  ushort_t* w2p = w1pf + 32768;

  hipLaunchKernelGGL(k_cnt, dim3(G), dim3(256), 0, stream, erow, cnt, E, G, NBIN);
  hipLaunchKernelGGL(k_scan1, dim3(nb2), dim3(256), 0, stream, cnt, cntoff, aux, M);
  hipLaunchKernelGGL(k_scan_aux, dim3(1), dim3(128), 0, stream, aux, nb2);
  hipLaunchKernelGGL(k_scan_add, dim3(nb2), dim3(256), 0, stream, cntoff, aux, M, E);
  hipLaunchKernelGGL(k_scatter1, dim3(G), dim3(256), 0, stream, erow, ecol_in, ew_in, cntoff, epk2, E, G, NBIN);
  hipLaunchKernelGGL(k_binsort, dim3(NBIN), dim3(256), 0, stream, cntoff, epk2, ip, epk, G, NBIN, N, E);
  hipLaunchKernelGGL(k_w1prep, dim3(128), dim3(256), 0, stream, W1, w1pf);
  hipLaunchKernelGGL(k_w2prep, dim3((4 * 3 * 64 * 8 + 255) / 256), dim3(256), 0, stream, W2, w2p);
  hipLaunchKernelGGL(k_gemm1, dim3((N + 63) / 64), dim3(256), 0, stream, x, w1pf, h0f8, N);
  hipLaunchKernelGGL(k_spmm1, dim3(N / 4), dim3(256), 0, stream, ip, (const long long*)epk, h0f8, b1, hbf);
  hipLaunchKernelGGL(k_gemm2, dim3((N + 63) / 64), dim3(256), 0, stream, hbf, w2p, h2f8, N);
  hipLaunchKernelGGL(k_spmm2lsm, dim3(N / 4), dim3(256), 0, stream, ip, (const long long*)epk, h2f8, b2, out);
}